// Round 11
// baseline (69.728 us; speedup 1.0000x reference)
//
#include <hip/hip_runtime.h>
#include <hip/hip_bf16.h>

#define LAMBDA 0.75f
#define CMID 256
#define DOUT 4096

typedef __attribute__((ext_vector_type(8))) short bf16x8;   // MFMA A/B operand
typedef __attribute__((ext_vector_type(4))) float f32x4;    // MFMA C/D operand

static inline __device__ short f2bf(float f) {
    __hip_bfloat16 h = __float2bfloat16(f);
    short s; __builtin_memcpy(&s, &h, 2);
    return s;
}
static inline __device__ unsigned pack2(float lo, float hi) {
    unsigned a = (unsigned short)f2bf(lo);
    unsigned b = (unsigned short)f2bf(hi);
    return a | (b << 16);
}

// ---------------------------------------------------------------------------
// Fused conv3x3(p=1)+bias+relu+hardshrink+pool, implicit GEMM via MFMA.
// ROUND-11 THEORY: rounds 6-9 were silently register-capped. Evidence:
// (256,4)->VGPR 64 (r5), (512,4)->VGPR 64 (r9): hipcc's 2nd launch_bounds arg
// behaves as WORKGROUPS/EU (16 resp. 32 waves/EU requested -> clamp 8 ->
// 512/8 = 64-VGPR cap). So (256,2) in r6-8 = 8 waves/EU = SAME 64 cap ->
// ~40 spilled regs -> scratch-stall-dominated ~51us, insensitive to phase-3
// edits. Fix: single-arg __launch_bounds__(256); usage (~85 regs) sets
// occupancy naturally (<=128 -> 4 waves/SIMD; LDS 22.4KB -> 4 blocks/CU).
// Register diet: (a) bias injected via dead k-slot s27 (weights carry bias,
// im2col carries 1.0) -> bias is FREE through the matrix unit, biasf[] gone;
// (b) software pipeline dropped (r7==r8 proved it neutral).
// Layout recap: im2col[g][col] uint4, conflict-free quarter-wave b128 reads;
// k-slot map s=g*8+j IDENTICAL on A and B sides (any HW k-bijection works):
//   g<3: ci=g, ky=j/3, kx=j%3 ; g==3: j<3 -> ci=j tap(2,2); j==3 -> BIAS
//   (x-side 1.0); j>4 -> zero both sides.
// ---------------------------------------------------------------------------
__global__ __launch_bounds__(256) void conv_pool_mfma(
    const float* __restrict__ x, const float* __restrict__ conv_w,
    const float* __restrict__ conv_b, float* __restrict__ part)
{
    __shared__ float raw[1632];           // [ci][r 0..3][idx 0..135], col=idx-4
    __shared__ uint4 im2col[4][256];      // [g][col] -> 8 bf16 k-slots

    const int bk = blockIdx.x;
    const int b  = bk >> 6;
    const int h0 = (bk & 63) * 2;
    const int t  = threadIdx.x;
    const int l  = t & 63;
    const int wv = t >> 6;
    const int lm = l & 15;
    const int g  = l >> 4;

    // ---- phase 1: stage raw x (zero-padded borders), coalesced ----
    for (int i = t; i < 1632; i += 256) {
        int ci  = i / 544;
        int rem = i - ci * 544;
        int r   = rem / 136;
        int idx = rem - r * 136;
        int hh  = h0 - 1 + r;
        int col = idx - 4;
        float v = 0.f;
        if ((unsigned)hh < 128u && (unsigned)col < 128u)
            v = x[(b * 3 + ci) * 16384 + hh * 128 + col];
        raw[i] = v;
    }

    // ---- weights as B-frags (col n = lm -> co); bias rides k-slot s27 ----
    bf16x8 wfrag[4];
    f32x4  pool[4];
    #pragma unroll
    for (int c = 0; c < 4; ++c) {
        const int ct = wv * 4 + c;
        const int co = ct * 16 + lm;
        const float* wp = conv_w + co * 27;
        float av[8];
        if (g < 3) {
            #pragma unroll
            for (int j = 0; j < 8; ++j) av[j] = wp[g * 9 + j];
        } else {
            av[0] = wp[8]; av[1] = wp[17]; av[2] = wp[26];
            av[3] = conv_b[co];               // bias * im2col's 1.0
            av[4] = av[5] = av[6] = av[7] = 0.f;
        }
        #pragma unroll
        for (int j = 0; j < 8; ++j) wfrag[c][j] = f2bf(av[j]);
        pool[c] = (f32x4){0.f, 0.f, 0.f, 0.f};
    }

    __syncthreads();

    // ---- phase 2: build im2col; thread t = column (out_r = t>>7, px = t&127) ----
    {
        const int out_r = t >> 7;
        const int px    = t & 127;
        const float* r0 = raw + 0 * 544 + out_r * 136 + px + 3;
        const float* r1 = raw + 1 * 544 + out_r * 136 + px + 3;
        const float* r2 = raw + 2 * 544 + out_r * 136 + px + 3;
        uint4 w;
        w.x = pack2(r0[0],   r0[1]);   w.y = pack2(r0[2],   r0[136]);
        w.z = pack2(r0[137], r0[138]); w.w = pack2(r0[272], r0[273]);
        im2col[0][t] = w;
        w.x = pack2(r1[0],   r1[1]);   w.y = pack2(r1[2],   r1[136]);
        w.z = pack2(r1[137], r1[138]); w.w = pack2(r1[272], r1[273]);
        im2col[1][t] = w;
        w.x = pack2(r2[0],   r2[1]);   w.y = pack2(r2[2],   r2[136]);
        w.z = pack2(r2[137], r2[138]); w.w = pack2(r2[272], r2[273]);
        im2col[2][t] = w;
        w.x = pack2(r0[274], r1[274]);
        w.y = pack2(r2[274], 1.0f);    // s26 = ci2 tap(2,2); s27 = 1.0 (bias)
        w.z = 0u;                      w.w = 0u;   // s28..s31 dead = 0
        im2col[3][t] = w;
    }

    __syncthreads();

    // ---- phase 3: 16 px-tiles x 4 co-tiles, zero C-in (bias in k-slot) ----
    f32x4 zf = (f32x4){0.f, 0.f, 0.f, 0.f};
    #pragma unroll
    for (int tile = 0; tile < 16; ++tile) {
        const uint4 xr = im2col[g][tile * 16 + lm];   // conflict-free b128
        bf16x8 xf; __builtin_memcpy(&xf, &xr, 16);
        #pragma unroll
        for (int c = 0; c < 4; ++c) {
            f32x4 acc = __builtin_amdgcn_mfma_f32_16x16x32_bf16(
                xf, wfrag[c], zf, 0, 0, 0);
            #pragma unroll
            for (int r = 0; r < 4; ++r)
                pool[c][r] += (acc[r] > LAMBDA) ? acc[r] : 0.f; // relu+hardshrink
        }
    }

    // ---- reduce over px: in-lane fold + xor16 + xor32; partial store ----
    #pragma unroll
    for (int c = 0; c < 4; ++c) {
        float s = (pool[c][0] + pool[c][1]) + (pool[c][2] + pool[c][3]);
        s += __shfl_xor(s, 16, 64);
        s += __shfl_xor(s, 32, 64);
        if (l < 16)
            part[bk * 256 + wv * 64 + c * 16 + lm] = s;
    }
}

// ---------------------------------------------------------------------------
// FC: reduce 64 per-block partials -> pooled[b], then
// out[b][d] = log_sigmoid(dot(pooled[b]/16384, fc_w[d]) + fc_b[d])
// ---------------------------------------------------------------------------
__global__ __launch_bounds__(256) void fc_kernel(
    const float* __restrict__ part, const float* __restrict__ fc_w,
    const float* __restrict__ fc_b, float* __restrict__ out)
{
    __shared__ float pool[CMID];
    const int b = blockIdx.y;
    const int t = threadIdx.x;

    float s = 0.f;
    const float* pp = part + b * 64 * 256 + t;
    #pragma unroll
    for (int j = 0; j < 64; ++j) s += pp[j * 256];
    pool[t] = s * (1.0f / 16384.0f);
    __syncthreads();

    const int d = blockIdx.x * 256 + t;
    const float4* wrow = (const float4*)(fc_w + d * CMID);
    float acc = fc_b[d];
    #pragma unroll 8
    for (int k4 = 0; k4 < CMID / 4; k4++) {
        float4 wv = wrow[k4];
        acc += wv.x * pool[k4 * 4 + 0] + wv.y * pool[k4 * 4 + 1]
             + wv.z * pool[k4 * 4 + 2] + wv.w * pool[k4 * 4 + 3];
    }
    float ls = fminf(acc, 0.f) - log1pf(expf(-fabsf(acc)));
    out[b * (int)DOUT + d] = ls;
}

// ---------------------------------------------------------------------------
extern "C" void kernel_launch(void* const* d_in, const int* in_sizes, int n_in,
                              void* d_out, int out_size, void* d_ws, size_t ws_size,
                              hipStream_t stream) {
    const float* x      = (const float*)d_in[0];   // [32,3,128,128]
    const float* conv_w = (const float*)d_in[1];   // [256,3,3,3]
    const float* conv_b = (const float*)d_in[2];   // [256]
    const float* fc_w   = (const float*)d_in[3];   // [4096,256]
    const float* fc_b   = (const float*)d_in[4];   // [4096]
    float* out  = (float*)d_out;                   // [32,4096]
    float* part = (float*)d_ws;                    // [2048][256] = 2 MB partials

    conv_pool_mfma<<<32 * 64, 256, 0, stream>>>(x, conv_w, conv_b, part);
    fc_kernel<<<dim3(16, 32), 256, 0, stream>>>(part, fc_w, fc_b, out);
}